// Round 12
// baseline (342.117 us; speedup 1.0000x reference)
//
#include <hip/hip_runtime.h>
#include <stdint.h>

#define N_NODES  100000
#define N_EDGES  1600000
#define IN_FEATS 128
#define HID      32
#define N_REL    5
#define N_BASES  2
#define N_PAIRS  4096

#define NB        196        // buckets of 512 dst nodes
#define BCAP      16384      // fixed slab per bucket (mean 8192, sigma ~90)
#define EPB       2048       // edges per scatter block (R4/R8-verified best)
#define SC_BLOCKS 782        // ceil(1600000/2048)
#define WP_BLOCKS 137        // weight-prep blocks + 1 flags block
#define NBSORT    392        // 2*NB bsort blocks (512 thr)
#define TD_BLOCKS 625        // transform-double blocks (512 thr, 2x5 groups each)

typedef __attribute__((ext_vector_type(8))) short short8;
typedef __attribute__((ext_vector_type(4))) float f32x4;

__device__ inline unsigned int pack_bf16(float a, float b) {
    unsigned int ua = __float_as_uint(a), ub = __float_as_uint(b);
    ua = (ua + 0x7fffu + ((ua >> 16) & 1u)) >> 16;
    ub = (ub + 0x7fffu + ((ub >> 16) & 1u)) >> 16;
    return ua | (ub << 16);
}

__device__ inline unsigned short bf16_1(float a) {
    unsigned int u = __float_as_uint(a);
    u = (u + 0x7fffu + ((u >> 16) & 1u)) >> 16;
    return (unsigned short)u;
}

// split pair (a,b) into bf16 hi word + bf16 lo (residual) word
__device__ inline void split_bf16_2(float a, float b, unsigned int& hi, unsigned int& lo) {
    unsigned int ha = bf16_1(a), hb = bf16_1(b);
    hi = ha | (hb << 16);
    float fa = __uint_as_float(ha << 16), fb = __uint_as_float(hb << 16);
    lo = pack_bf16(a - fa, b - fb);
}

// ---------------- k1: edge scatter (0..781) + weight prep (782..917) + flags (918) ----------
// scatter record: x = (dst&511)<<23 | (src<<4) | etype, y = mask fp32
// flags[v]=1 iff v in users/items (MLP reads concat there).
// flag2 starts as flags; agg1 adds in-neighbors of marked nodes (L2 active set).

#define SMEM_BYTES 23856

__global__ __launch_bounds__(256) void k_scatter_wprep(
    const int* __restrict__ src, const int* __restrict__ dst,
    const int* __restrict__ etype, const float* __restrict__ mask,
    int* __restrict__ gcur, int2* __restrict__ ebuf,
    const float* __restrict__ V1, const float* __restrict__ comp1, const float* __restrict__ loop1,
    const float* __restrict__ V2, const float* __restrict__ loop2,
    const float* __restrict__ V3, const float* __restrict__ loop3,
    unsigned short* __restrict__ Wbf1, unsigned short* __restrict__ Wcat2,
    unsigned short* __restrict__ Wcat3,
    const int* __restrict__ uidx, const int* __restrict__ iidx,
    unsigned char* __restrict__ flags, unsigned char* __restrict__ flag2,
    int* __restrict__ cnt2) {
    __shared__ __attribute__((aligned(16))) char smem[SMEM_BYTES];
    int b = blockIdx.x;
    int t = threadIdx.x;
    if (b < SC_BLOCKS) {
        // ---------- scatter with block-local counting sort (exact R8) ----------
        int2*  srec    = (int2*)smem;                    // 16384
        short* sb      = (short*)(smem + 16384);         // 4096  -> 20480
        int*   lh      = (int*)(smem + 20480);           // 784   -> 21264
        int*   lex     = (int*)(smem + 21264);           // 784   -> 22048
        int*   gbase   = (int*)(smem + 22048);           // 784   -> 22832
        int*   scanbuf = (int*)(smem + 22832);           // 1024  -> 23856
        int e0 = b * EPB;
        if (t < NB) lh[t] = 0;
        __syncthreads();
        int2 rec[8];
        int  bk[8];
#pragma unroll
        for (int i = 0; i < 8; i++) {
            int e = e0 + t + i * 256;
            if (e < N_EDGES) {
                int d = dst[e];
                bk[i] = d >> 9;
                rec[i].x = ((d & 511) << 23) | (src[e] << 4) | etype[e];
                rec[i].y = __float_as_int(mask[e]);
                atomicAdd(&lh[bk[i]], 1);
            } else bk[i] = -1;
        }
        __syncthreads();
        int cnt = (t < NB) ? lh[t] : 0;
        scanbuf[t] = cnt;
        __syncthreads();
        for (int off = 1; off < 256; off <<= 1) {
            int v = (t >= off) ? scanbuf[t - off] : 0;
            __syncthreads();
            scanbuf[t] += v;
            __syncthreads();
        }
        if (t < NB) {
            lex[t] = scanbuf[t] - cnt;
            gbase[t] = t * BCAP + (cnt ? atomicAdd(&gcur[t], cnt) : 0);
            lh[t] = 0;   // reuse as sort cursor
        }
        __syncthreads();
#pragma unroll
        for (int i = 0; i < 8; i++) {
            if (bk[i] >= 0) {
                int p = lex[bk[i]] + atomicAdd(&lh[bk[i]], 1);
                srec[p] = rec[i];
                sb[p] = (short)bk[i];
            }
        }
        __syncthreads();
        int total = scanbuf[NB - 1];
        for (int idx = t; idx < total; idx += 256) {
            int bb = sb[idx];
            ebuf[gbase[bb] + (idx - lex[bb])] = srec[idx];
        }
        return;
    }
    // ---------- weight prep / flags ----------
    int wb = b - SC_BLOCKS;
    if (wb == 136) {
        unsigned int* f4 = (unsigned int*)flags;
        unsigned int* g4 = (unsigned int*)flag2;
        for (int i = t; i < 25000; i += 256) { f4[i] = 0u; g4[i] = 0u; }
        if (t == 0) *cnt2 = 0;
        __syncthreads();
        for (int i = t; i < N_PAIRS; i += 256) {
            int u = uidx[i], it = iidx[i];
            flags[u] = 1; flags[it] = 1;
            flag2[u] = 1; flag2[it] = 1;
        }
        return;
    }
    if (wb < 96) {
        int idx = wb * 256 + t;
        if (idx >= 192 * IN_FEATS) return;
        int j = idx / IN_FEATS, k = idx % IN_FEATS;
        float v;
        if (j < 160) {
            int r = j >> 5, o = j & 31;
            v = comp1[r * 2 + 0] * V1[(size_t)(0 * IN_FEATS + k) * 32 + o]
              + comp1[r * 2 + 1] * V1[(size_t)(1 * IN_FEATS + k) * 32 + o];
        } else {
            v = loop1[k * 32 + (j - 160)];
        }
        Wbf1[idx] = bf16_1(v);
        return;
    }
    const float *V, *loopw;
    unsigned short* Wc;
    int idx;
    if (wb < 116) { V = V2; loopw = loop2; Wc = Wcat2; idx = (wb - 96) * 256 + t; }
    else          { V = V3; loopw = loop3; Wc = Wcat3; idx = (wb - 116) * 256 + t; }
    if (idx >= 32 * 160) return;
    int col = idx / 160, k = idx % 160;
    int seg = k >> 5, inner = k & 31;
    float v;
    if (seg < 2)      v = V[inner * 32 + col];           // basis 0 (hi, lo)
    else if (seg < 4) v = V[(32 + inner) * 32 + col];    // basis 1 (hi, lo)
    else              v = loopw[inner * 32 + col];       // self-loop
    Wc[idx] = bf16_1(v);
}

// ---------------- k2: bsort (0..391) || transform L1 (392..1016), 512 thr (R10 exact) ----------

#define SMEM2_BYTES 19456    // 2 x (As 4352 + tb 5376) = 19456 >= bsort's 7176

__global__ __launch_bounds__(512) void k_bsort_tl1(
    const int* __restrict__ gcur, const int2* __restrict__ ebuf,
    int2* __restrict__ esort, int* __restrict__ offsets,
    const float* __restrict__ xin,
    const unsigned short* __restrict__ Wbf, const float* __restrict__ bias,
    unsigned short* __restrict__ xs16, float* __restrict__ aggout) {
    __shared__ __attribute__((aligned(16))) char smem2[SMEM2_BYTES];
    int b = blockIdx.x;
    int t = threadIdx.x;
    if (b < NBSORT) {
        // ---------- per-half-bucket counting sort -> CSR ----------
        int* hist = (int*)smem2;                 // 2048
        int* incl = (int*)(smem2 + 2048);        // 2048 -> 4096
        int* cur  = (int*)(smem2 + 4096);        // 2048 -> 6144
        int* bs   = (int*)(smem2 + 6144);        // 1024 -> 7168
        int* sBC  = (int*)(smem2 + 7168);        // [0]=sBase [1]=sCnt
        int bb = b >> 1, h = b & 1;
        if (t < 256) bs[t] = (t < NB) ? gcur[t] : 0;
        __syncthreads();
        for (int off = 1; off < 256; off <<= 1) {
            int v = 0;
            if (t < 256 && t >= off) v = bs[t - off];
            __syncthreads();
            if (t < 256) bs[t] += v;
            __syncthreads();
        }
        if (t == 0) { sBC[1] = gcur[bb]; sBC[0] = bs[bb] - gcur[bb]; }
        hist[t] = 0;
        __syncthreads();
        int cnt = sBC[1], gbase = sBC[0];
        const int2* slab = ebuf + (size_t)bb * BCAP;
        for (int e = t; e < cnt; e += 512) {
            int dl = ((unsigned)slab[e].x) >> 23;
            atomicAdd(&hist[dl], 1);
        }
        __syncthreads();
        incl[t] = hist[t];
        __syncthreads();
        for (int off = 1; off < 512; off <<= 1) {
            int v = 0;
            if (t >= off) v = incl[t - off];
            __syncthreads();
            incl[t] += v;
            __syncthreads();
        }
        int ex = incl[t] - hist[t];
        cur[t] = ex;
        if ((t >> 8) == h) {
            int n = (bb << 9) + t;
            if (n <= N_NODES) offsets[n] = gbase + ex;
        }
        if (bb == NB - 1 && h == 1 && t == 0) offsets[N_NODES] = N_EDGES;
        __syncthreads();
        for (int e = t; e < cnt; e += 512) {
            int2 pk = slab[e];
            int dl = ((unsigned)pk.x) >> 23;
            if ((dl >> 8) == h) {
                int pos = gbase + atomicAdd(&cur[dl], 1);
                int2 rec;
                rec.x = pk.x & 0x7fffff;
                rec.y = pk.y;
                esort[pos] = rec;
            }
        }
        return;
    }
    // ---------- transform L1: two independent 256-thread halves ----------
    int half = t >> 8;                 // 0 / 1
    int tl   = t & 255;
    char* basep = smem2 + half * 9728;
    unsigned short* As = (unsigned short*)basep;          // 16*136*2 = 4352 B
    unsigned short* tb = (unsigned short*)(basep + 4352); // 16*168*2 = 5376 B
    int bb = (b - NBSORT) * 2 + half;  // 0..1249
    int wv = tl >> 6, lane = tl & 63;
    int q = lane >> 4, n16 = lane & 15;
    short8 bfr[3][4];
#pragma unroll
    for (int i = 0; i < 3; i++) {
        int tt = wv * 3 + i;
#pragma unroll
        for (int ks = 0; ks < 4; ks++)
            bfr[i][ks] = *(const short8*)(Wbf + (tt * 16 + n16) * 128 + ks * 32 + q * 8);
    }
    float bv0 = bias[n16], bv1 = bias[16 + n16];
    int node_l = tl >> 4;
    int seg    = tl & 15;
    int g0 = bb * 5;
    float4 p0, p1;
    {
        const float* xr = xin + ((size_t)(g0 * 16 + node_l)) * 128 + seg * 8;
        p0 = *(const float4*)xr;
        p1 = *(const float4*)(xr + 4);
    }
    for (int gi = 0; gi < 5; gi++) {
        int g = g0 + gi;
        int n0 = g * 16;
        __syncthreads();   // As + tb free [both halves in lockstep]
        {
            uint4 v;
            v.x = pack_bf16(p0.x, p0.y);
            v.y = pack_bf16(p0.z, p0.w);
            v.z = pack_bf16(p1.x, p1.y);
            v.w = pack_bf16(p1.z, p1.w);
            *(uint4*)(As + node_l * 136 + seg * 8) = v;
        }
        __syncthreads();
        if (gi + 1 < 5) {
            const float* xr = xin + ((size_t)((g + 1) * 16 + node_l)) * 128 + seg * 8;
            p0 = *(const float4*)xr;
            p1 = *(const float4*)(xr + 4);
        }
        short8 afr[4];
#pragma unroll
        for (int ks = 0; ks < 4; ks++)
            afr[ks] = *(const short8*)(As + n16 * 136 + ks * 32 + q * 8);
        f32x4 d[3];
        f32x4 z = {0.f, 0.f, 0.f, 0.f};
#pragma unroll
        for (int i = 0; i < 3; i++) d[i] = z;
#pragma unroll
        for (int i = 0; i < 3; i++)
#pragma unroll
            for (int ks = 0; ks < 4; ks++)
                d[i] = __builtin_amdgcn_mfma_f32_16x16x32_bf16(afr[ks], bfr[i][ks], d[i], 0, 0, 0);
        // epilogue: tts 0..9 -> LDS transpose; tts 10,11 -> aggA direct (f32)
#pragma unroll
        for (int i = 0; i < 3; i++) {
            int tt = wv * 3 + i;
            if (tt < 10) {
#pragma unroll
                for (int r = 0; r < 4; r++)
                    tb[(q * 4 + r) * 168 + tt * 16 + n16] = bf16_1(d[i][r]);
            } else {
                float bv = (tt == 10) ? bv0 : bv1;
                int o = (tt - 10) * 16 + n16;
#pragma unroll
                for (int r = 0; r < 4; r++) {
                    int node = n0 + q * 4 + r;
                    aggout[(size_t)node * 32 + o] = d[i][r] + bv;
                }
            }
        }
        __syncthreads();
        // coalesced xs16 flush
        for (int c = tl; c < 320; c += 256) {
            int node_i = c / 20, part = c % 20;
            short8 vv = *(const short8*)(tb + node_i * 168 + part * 8);
            *(short8*)(xs16 + (size_t)(n0 + node_i) * 160 + part * 8) = vv;
        }
    }
}

// ---------------- layer-1 aggregation + flag2 marking ----------------
// For marked dst nodes, mark flag2[src] of every in-edge: those srcs are the
// only nodes whose h2 is gathered by the (restricted) layer 3.

__global__ __launch_bounds__(256) void k_agg1(
    const int* __restrict__ offsets, const int2* __restrict__ esort,
    const unsigned int* __restrict__ xrel16, const float* __restrict__ agg,
    float* __restrict__ concat, unsigned int* __restrict__ hrel_out,
    const unsigned char* __restrict__ flags, unsigned char* __restrict__ flag2) {
    int v = blockIdx.x * 32 + (threadIdx.x >> 3);
    int o = threadIdx.x & 7;
    int s0 = offsets[v], s1 = offsets[v + 1];
    bool fmark = flags[v] && (o == 0);
    float4 a0 = *(const float4*)(agg + (size_t)v * 32 + o * 4);
    float acc0 = a0.x, acc1 = a0.y, acc2 = a0.z, acc3 = a0.w;
    int last = s1 - 1;
    for (int e = s0; e < s1; e += 16) {
        int addr[16];
        float m[16];
#pragma unroll
        for (int i = 0; i < 16; i++) {
            int ei = e + i;
            int ec = (ei <= last) ? ei : last;
            int2 pk = esort[ec];
            int low = pk.x;
            addr[i] = (low >> 4) * 80 + (low & 15) * 16;
            m[i] = (ei <= last) ? __int_as_float(pk.y) : 0.f;
            if (fmark && ei <= last) flag2[(unsigned)low >> 4] = 1;
        }
        uint2 xw[16];
#pragma unroll
        for (int i = 0; i < 16; i++)
            xw[i] = *(const uint2*)(xrel16 + (unsigned)addr[i] + o * 2);
#pragma unroll
        for (int i = 0; i < 16; i++) {
            float f0 = __uint_as_float(xw[i].x << 16);
            float f1 = __uint_as_float(xw[i].x & 0xffff0000u);
            float f2 = __uint_as_float(xw[i].y << 16);
            float f3 = __uint_as_float(xw[i].y & 0xffff0000u);
            acc0 = fmaf(m[i], f0, acc0);
            acc1 = fmaf(m[i], f1, acc1);
            acc2 = fmaf(m[i], f2, acc2);
            acc3 = fmaf(m[i], f3, acc3);
        }
    }
    float4 r;
    r.x = tanhf(acc0); r.y = tanhf(acc1); r.z = tanhf(acc2); r.w = tanhf(acc3);
    if (flags[v])
        *(float4*)(concat + (size_t)v * 96 + o * 4) = r;
    hrel_out[v * 16 + o * 2]     = pack_bf16(r.x, r.y);
    hrel_out[v * 16 + o * 2 + 1] = pack_bf16(r.z, r.w);
}

// ---------------- compact flag2 -> nlist2 (+count) ----------------

__global__ __launch_bounds__(256) void k_compact(
    const unsigned char* __restrict__ flag2, int* __restrict__ nlist2,
    int* __restrict__ cnt2) {
    int i = blockIdx.x * 256 + threadIdx.x;
    if (i < N_NODES && flag2[i]) {
        int pos = atomicAdd(cnt2, 1);
        nlist2[pos] = i;
    }
}

// ---------------- layer 2 COMPACT: only flag2-active nodes (~73%) ----------------
// Indirect node list (agg3s-verified structure). h2's hrel is gathered by L3
// only at flag2 nodes; concat[32..64] read only at flags nodes (⊆ flag2).

__global__ __launch_bounds__(256) void k_agg2c(
    const int* __restrict__ offsets, const int2* __restrict__ esort,
    const unsigned int* __restrict__ hrel_in, const float* __restrict__ comp,
    const unsigned short* __restrict__ Wcat, const float* __restrict__ bias,
    float* __restrict__ concat, unsigned int* __restrict__ hrel_out,
    const unsigned char* __restrict__ flags,
    const int* __restrict__ nlist2, const int* __restrict__ cnt2) {
    int cnt = *cnt2;
    if (blockIdx.x * 32 >= cnt) return;
    __shared__ unsigned int hbf[32][84];
    __shared__ float2 cLds[5];
    __shared__ int nlist[32];
    int t = threadIdx.x;
    if (t < 5) cLds[t] = ((const float2*)comp)[t];
    if (t < 32) {
        int slot = blockIdx.x * 32 + t;
        nlist[t] = nlist2[(slot < cnt) ? slot : 0];   // pad with first active node (dup benign)
    }
    __syncthreads();
    int nl = t >> 3;
    int v = nlist[nl];
    int o = t & 7;
    int s0 = offsets[v], s1 = offsets[v + 1];
    float y00 = 0.f, y01 = 0.f, y02 = 0.f, y03 = 0.f;
    float y10 = 0.f, y11 = 0.f, y12 = 0.f, y13 = 0.f;
    int last = s1 - 1;
    for (int e = s0; e < s1; e += 16) {
        int addr[16];
        float c0[16], c1[16];
#pragma unroll
        for (int i = 0; i < 16; i++) {
            int ei = e + i;
            int ec = (ei <= last) ? ei : last;
            int2 pk = esort[ec];
            int low = pk.x;
            addr[i] = low & 0x7ffff0;            // src*16 (uint units)
            float2 cc = cLds[low & 15];
            float m = (ei <= last) ? __int_as_float(pk.y) : 0.f;
            c0[i] = m * cc.x;
            c1[i] = m * cc.y;
        }
        uint2 xw[16];
#pragma unroll
        for (int i = 0; i < 16; i++)
            xw[i] = *(const uint2*)(hrel_in + (unsigned)addr[i] + o * 2);
#pragma unroll
        for (int i = 0; i < 16; i++) {
            float f0 = __uint_as_float(xw[i].x << 16);
            float f1 = __uint_as_float(xw[i].x & 0xffff0000u);
            float f2 = __uint_as_float(xw[i].y << 16);
            float f3 = __uint_as_float(xw[i].y & 0xffff0000u);
            y00 = fmaf(c0[i], f0, y00); y10 = fmaf(c1[i], f0, y10);
            y01 = fmaf(c0[i], f1, y01); y11 = fmaf(c1[i], f1, y11);
            y02 = fmaf(c0[i], f2, y02); y12 = fmaf(c1[i], f2, y12);
            y03 = fmaf(c0[i], f3, y03); y13 = fmaf(c1[i], f3, y13);
        }
    }
    unsigned int hi, lo;
    split_bf16_2(y00, y01, hi, lo);
    hbf[nl][o * 2]          = hi;  hbf[nl][16 + o * 2]     = lo;
    split_bf16_2(y02, y03, hi, lo);
    hbf[nl][o * 2 + 1]      = hi;  hbf[nl][16 + o * 2 + 1] = lo;
    split_bf16_2(y10, y11, hi, lo);
    hbf[nl][32 + o * 2]     = hi;  hbf[nl][48 + o * 2]     = lo;
    split_bf16_2(y12, y13, hi, lo);
    hbf[nl][32 + o * 2 + 1] = hi;  hbf[nl][48 + o * 2 + 1] = lo;
    *(uint2*)&hbf[nl][64 + o * 2] = *(const uint2*)(hrel_in + v * 16 + o * 2);
    __syncthreads();
    int wv = t >> 6, lane = t & 63;
    int q = lane >> 4, n16 = lane & 15;
    int gg = wv & 1;
    int tt = wv >> 1;
    f32x4 d = {0.f, 0.f, 0.f, 0.f};
#pragma unroll
    for (int ks = 0; ks < 5; ks++) {
        short8 afr = *(const short8*)&hbf[gg * 16 + n16][ks * 16 + q * 4];
        short8 bfr = *(const short8*)(Wcat + (tt * 16 + n16) * 160 + ks * 32 + q * 8);
        d = __builtin_amdgcn_mfma_f32_16x16x32_bf16(afr, bfr, d, 0, 0, 0);
    }
    float bv = bias[tt * 16 + n16];
    int base = gg * 16 + q * 4;
#pragma unroll
    for (int r = 0; r < 4; r++) {
        int node = nlist[base + r];
        float h = tanhf(d[r] + bv);
        if (flags[node])
            concat[(size_t)node * 96 + 32 + tt * 16 + n16] = h;
        ((unsigned short*)hrel_out)[node * 32 + tt * 16 + n16] = bf16_1(h);
    }
}

// ---------------- layer 3 RESTRICTED: only the 8192 MLP-referenced nodes ----------

__global__ __launch_bounds__(256) void k_agg3s(
    const int* __restrict__ offsets, const int2* __restrict__ esort,
    const unsigned int* __restrict__ hrel_in, const float* __restrict__ comp,
    const unsigned short* __restrict__ Wcat, const float* __restrict__ bias,
    const int* __restrict__ uidx, const int* __restrict__ iidx,
    float* __restrict__ concat) {
    __shared__ unsigned int hbf[32][84];
    __shared__ float2 cLds[5];
    __shared__ int nlist[32];
    int t = threadIdx.x;
    if (t < 5) cLds[t] = ((const float2*)comp)[t];
    if (t < 32) {
        int slot = blockIdx.x * 32 + t;   // 256 blocks x 32 = 8192 slots exact
        nlist[t] = (slot < N_PAIRS) ? uidx[slot] : iidx[slot - N_PAIRS];
    }
    __syncthreads();
    int nl = t >> 3;
    int v = nlist[nl];
    int o = t & 7;
    int s0 = offsets[v], s1 = offsets[v + 1];
    float y00 = 0.f, y01 = 0.f, y02 = 0.f, y03 = 0.f;
    float y10 = 0.f, y11 = 0.f, y12 = 0.f, y13 = 0.f;
    int last = s1 - 1;
    for (int e = s0; e < s1; e += 16) {
        int addr[16];
        float c0[16], c1[16];
#pragma unroll
        for (int i = 0; i < 16; i++) {
            int ei = e + i;
            int ec = (ei <= last) ? ei : last;
            int2 pk = esort[ec];
            int low = pk.x;
            addr[i] = low & 0x7ffff0;
            float2 cc = cLds[low & 15];
            float m = (ei <= last) ? __int_as_float(pk.y) : 0.f;
            c0[i] = m * cc.x;
            c1[i] = m * cc.y;
        }
        uint2 xw[16];
#pragma unroll
        for (int i = 0; i < 16; i++)
            xw[i] = *(const uint2*)(hrel_in + (unsigned)addr[i] + o * 2);
#pragma unroll
        for (int i = 0; i < 16; i++) {
            float f0 = __uint_as_float(xw[i].x << 16);
            float f1 = __uint_as_float(xw[i].x & 0xffff0000u);
            float f2 = __uint_as_float(xw[i].y << 16);
            float f3 = __uint_as_float(xw[i].y & 0xffff0000u);
            y00 = fmaf(c0[i], f0, y00); y10 = fmaf(c1[i], f0, y10);
            y01 = fmaf(c0[i], f1, y01); y11 = fmaf(c1[i], f1, y11);
            y02 = fmaf(c0[i], f2, y02); y12 = fmaf(c1[i], f2, y12);
            y03 = fmaf(c0[i], f3, y03); y13 = fmaf(c1[i], f3, y13);
        }
    }
    unsigned int hi, lo;
    split_bf16_2(y00, y01, hi, lo);
    hbf[nl][o * 2]          = hi;  hbf[nl][16 + o * 2]     = lo;
    split_bf16_2(y02, y03, hi, lo);
    hbf[nl][o * 2 + 1]      = hi;  hbf[nl][16 + o * 2 + 1] = lo;
    split_bf16_2(y10, y11, hi, lo);
    hbf[nl][32 + o * 2]     = hi;  hbf[nl][48 + o * 2]     = lo;
    split_bf16_2(y12, y13, hi, lo);
    hbf[nl][32 + o * 2 + 1] = hi;  hbf[nl][48 + o * 2 + 1] = lo;
    *(uint2*)&hbf[nl][64 + o * 2] = *(const uint2*)(hrel_in + v * 16 + o * 2);
    __syncthreads();
    int wv = t >> 6, lane = t & 63;
    int q = lane >> 4, n16 = lane & 15;
    int gg = wv & 1;
    int tt = wv >> 1;
    f32x4 d = {0.f, 0.f, 0.f, 0.f};
#pragma unroll
    for (int ks = 0; ks < 5; ks++) {
        short8 afr = *(const short8*)&hbf[gg * 16 + n16][ks * 16 + q * 4];
        short8 bfr = *(const short8*)(Wcat + (tt * 16 + n16) * 160 + ks * 32 + q * 8);
        d = __builtin_amdgcn_mfma_f32_16x16x32_bf16(afr, bfr, d, 0, 0, 0);
    }
    float bv = bias[tt * 16 + n16];
    int base = gg * 16 + q * 4;
#pragma unroll
    for (int r = 0; r < 4; r++) {
        int node = nlist[base + r];
        float h = tanhf(d[r] + bv);
        concat[(size_t)node * 96 + 64 + tt * 16 + n16] = h;
    }
}

// ---------------- MLP head ----------------

__global__ void k_mlp(const float* __restrict__ concat, const int* __restrict__ uidx,
                      const int* __restrict__ iidx,
                      const float* __restrict__ w1, const float* __restrict__ bw1,
                      const float* __restrict__ w2, const float* __restrict__ bw2,
                      float* __restrict__ out) {
    __shared__ float feats[192];
    __shared__ float red[2];
    int p = blockIdx.x;
    int t = threadIdx.x;   // 128 threads
    int u = uidx[p], it = iidx[p];
    for (int k = t; k < 192; k += 128)
        feats[k] = (k < 96) ? concat[(size_t)u * 96 + k] : concat[(size_t)it * 96 + (k - 96)];
    __syncthreads();
    float acc = bw1[t];
    for (int k = 0; k < 192; k++) acc += feats[k] * w1[k * 128 + t];
    float h = fmaxf(acc, 0.f);
    float part = h * w2[t];
    for (int off = 32; off > 0; off >>= 1) part += __shfl_down(part, off, 64);
    if ((t & 63) == 0) red[t >> 6] = part;
    __syncthreads();
    if (t == 0) out[p] = red[0] + red[1] + bw2[0];
}

// ---------------- launch ----------------

extern "C" void kernel_launch(void* const* d_in, const int* in_sizes, int n_in,
                              void* d_out, int out_size, void* d_ws, size_t ws_size,
                              hipStream_t stream) {
    const float* x         = (const float*)d_in[0];
    const float* edge_mask = (const float*)d_in[1];
    const int*   etype     = (const int*)d_in[2];
    const int*   src       = (const int*)d_in[3];
    const int*   dst       = (const int*)d_in[4];
    const int*   users_idx = (const int*)d_in[5];
    const int*   items_idx = (const int*)d_in[6];
    const float* V1        = (const float*)d_in[7];
    const float* comp1     = (const float*)d_in[8];
    const float* loop1     = (const float*)d_in[9];
    const float* b1        = (const float*)d_in[10];
    const float* V2        = (const float*)d_in[11];
    const float* comp2     = (const float*)d_in[12];
    const float* loop2     = (const float*)d_in[13];
    const float* b2        = (const float*)d_in[14];
    const float* V3        = (const float*)d_in[15];
    const float* comp3     = (const float*)d_in[16];
    const float* loop3     = (const float*)d_in[17];
    const float* b3        = (const float*)d_in[18];
    const float* w1        = (const float*)d_in[19];
    const float* bw1       = (const float*)d_in[20];
    const float* w2        = (const float*)d_in[21];
    const float* bw2       = (const float*)d_in[22];
    float* out = (float*)d_out;

    uintptr_t w = (uintptr_t)d_ws;
    auto al = [&](size_t bytes) { uintptr_t p = (w + 255) & ~(uintptr_t)255; w = p + bytes; return p; };
    int*   gcur    = (int*)al(sizeof(int) * NB);
    unsigned char* flags = (unsigned char*)al(100000);
    unsigned char* flag2 = (unsigned char*)al(100000);
    int*   cnt2    = (int*)al(sizeof(int));
    int*   nlist2  = (int*)al(sizeof(int) * N_NODES);
    int*   offsets = (int*)al(sizeof(int) * (N_NODES + 1));
    int2*  ebuf    = (int2*)al(sizeof(int2) * (size_t)NB * BCAP);
    unsigned int* xs16  = (unsigned int*)al(sizeof(unsigned int) * (size_t)N_NODES * 80);
    unsigned int* hrel1 = (unsigned int*)al(sizeof(unsigned int) * (size_t)N_NODES * 16);
    unsigned int* hrel2 = (unsigned int*)al(sizeof(unsigned int) * (size_t)N_NODES * 16);
    int2*  esort   = (int2*)al(sizeof(int2) * N_EDGES);
    unsigned short* Wbf1  = (unsigned short*)al(sizeof(unsigned short) * 192 * IN_FEATS);
    unsigned short* Wcat2 = (unsigned short*)al(sizeof(unsigned short) * 32 * 160);
    unsigned short* Wcat3 = (unsigned short*)al(sizeof(unsigned short) * 32 * 160);
    float* aggA    = (float*)al(sizeof(float) * (size_t)N_NODES * 32);
    float* concat  = (float*)al(sizeof(float) * (size_t)N_NODES * 96);

    hipMemsetAsync(gcur, 0, sizeof(int) * NB, stream);

    // k1: scatter + weight prep + flags/flag2 init
    k_scatter_wprep<<<SC_BLOCKS + WP_BLOCKS, 256, 0, stream>>>(
        src, dst, etype, edge_mask, gcur, ebuf,
        V1, comp1, loop1, V2, loop2, V3, loop3, Wbf1, Wcat2, Wcat3,
        users_idx, items_idx, flags, flag2, cnt2);
    // k2: CSR bucket-sort || transform L1 (R10 512-thr version)
    k_bsort_tl1<<<NBSORT + TD_BLOCKS, 512, 0, stream>>>(
        gcur, ebuf, esort, offsets,
        x, Wbf1, b1, (unsigned short*)xs16, aggA);

    const int agrid = N_NODES / 32;   // 3125, exact

    // layer 1 aggregation -> h1; marks flag2[src] for marked dst nodes
    k_agg1<<<agrid, 256, 0, stream>>>(offsets, esort, xs16, aggA, concat, hrel1,
                                      flags, flag2);
    // compact flag2 -> nlist2
    k_compact<<<(N_NODES + 255) / 256, 256, 0, stream>>>(flag2, nlist2, cnt2);
    // layer 2: only flag2-active nodes (~73%)
    k_agg2c<<<agrid, 256, 0, stream>>>(offsets, esort, hrel1, comp2, Wcat2, b2,
                                       concat, hrel2, flags, nlist2, cnt2);
    // layer 3: only the 8192 MLP-referenced nodes
    k_agg3s<<<256, 256, 0, stream>>>(offsets, esort, hrel2, comp3, Wcat3, b3,
                                     users_idx, items_idx, concat);

    k_mlp<<<N_PAIRS, 128, 0, stream>>>(concat, users_idx, items_idx, w1, bw1, w2, bw2, out);
}

// Round 13
// 299.012 us; speedup vs baseline: 1.1442x; 1.1442x over previous
//
#include <hip/hip_runtime.h>
#include <stdint.h>

#define N_NODES  100000
#define N_EDGES  1600000
#define IN_FEATS 128
#define HID      32
#define N_REL    5
#define N_BASES  2
#define N_PAIRS  4096

#define NB        196        // buckets of 512 dst nodes
#define BCAP      16384      // fixed slab per bucket (mean 8192, sigma ~90)
#define EPB       2048       // edges per scatter block (R4/R8-verified best)
#define SC_BLOCKS 782        // ceil(1600000/2048)
#define WP_BLOCKS 137        // weight-prep blocks + 1 flags block
#define NBSORT    392        // 2*NB bsort blocks (512 thr)
#define TD_BLOCKS 625        // transform-double blocks (512 thr, 2x5 groups each)

typedef __attribute__((ext_vector_type(8))) short short8;
typedef __attribute__((ext_vector_type(4))) float f32x4;

__device__ inline unsigned int pack_bf16(float a, float b) {
    unsigned int ua = __float_as_uint(a), ub = __float_as_uint(b);
    ua = (ua + 0x7fffu + ((ua >> 16) & 1u)) >> 16;
    ub = (ub + 0x7fffu + ((ub >> 16) & 1u)) >> 16;
    return ua | (ub << 16);
}

__device__ inline unsigned short bf16_1(float a) {
    unsigned int u = __float_as_uint(a);
    u = (u + 0x7fffu + ((u >> 16) & 1u)) >> 16;
    return (unsigned short)u;
}

// split pair (a,b) into bf16 hi word + bf16 lo (residual) word
__device__ inline void split_bf16_2(float a, float b, unsigned int& hi, unsigned int& lo) {
    unsigned int ha = bf16_1(a), hb = bf16_1(b);
    hi = ha | (hb << 16);
    float fa = __uint_as_float(ha << 16), fb = __uint_as_float(hb << 16);
    lo = pack_bf16(a - fa, b - fb);
}

// ---------------- k1: edge scatter (0..781) + weight prep (782..917) + flags (918) ----------
// scatter record: x = (dst&511)<<23 | (src<<4) | etype, y = mask fp32
// flags[v]=1 iff v appears in users_idx/items_idx: concat f32 is only read by
// the MLP for those nodes, so agg passes skip concat stores elsewhere.

#define SMEM_BYTES 23856

__global__ __launch_bounds__(256) void k_scatter_wprep(
    const int* __restrict__ src, const int* __restrict__ dst,
    const int* __restrict__ etype, const float* __restrict__ mask,
    int* __restrict__ gcur, int2* __restrict__ ebuf,
    const float* __restrict__ V1, const float* __restrict__ comp1, const float* __restrict__ loop1,
    const float* __restrict__ V2, const float* __restrict__ loop2,
    const float* __restrict__ V3, const float* __restrict__ loop3,
    unsigned short* __restrict__ Wbf1, unsigned short* __restrict__ Wcat2,
    unsigned short* __restrict__ Wcat3,
    const int* __restrict__ uidx, const int* __restrict__ iidx,
    unsigned char* __restrict__ flags) {
    __shared__ __attribute__((aligned(16))) char smem[SMEM_BYTES];
    int b = blockIdx.x;
    int t = threadIdx.x;
    if (b < SC_BLOCKS) {
        // ---------- scatter with block-local counting sort (exact R8) ----------
        int2*  srec    = (int2*)smem;                    // 16384
        short* sb      = (short*)(smem + 16384);         // 4096  -> 20480
        int*   lh      = (int*)(smem + 20480);           // 784   -> 21264
        int*   lex     = (int*)(smem + 21264);           // 784   -> 22048
        int*   gbase   = (int*)(smem + 22048);           // 784   -> 22832
        int*   scanbuf = (int*)(smem + 22832);           // 1024  -> 23856
        int e0 = b * EPB;
        if (t < NB) lh[t] = 0;
        __syncthreads();
        int2 rec[8];
        int  bk[8];
#pragma unroll
        for (int i = 0; i < 8; i++) {
            int e = e0 + t + i * 256;
            if (e < N_EDGES) {
                int d = dst[e];
                bk[i] = d >> 9;
                rec[i].x = ((d & 511) << 23) | (src[e] << 4) | etype[e];
                rec[i].y = __float_as_int(mask[e]);
                atomicAdd(&lh[bk[i]], 1);
            } else bk[i] = -1;
        }
        __syncthreads();
        int cnt = (t < NB) ? lh[t] : 0;
        scanbuf[t] = cnt;
        __syncthreads();
        for (int off = 1; off < 256; off <<= 1) {
            int v = (t >= off) ? scanbuf[t - off] : 0;
            __syncthreads();
            scanbuf[t] += v;
            __syncthreads();
        }
        if (t < NB) {
            lex[t] = scanbuf[t] - cnt;
            gbase[t] = t * BCAP + (cnt ? atomicAdd(&gcur[t], cnt) : 0);
            lh[t] = 0;   // reuse as sort cursor
        }
        __syncthreads();
#pragma unroll
        for (int i = 0; i < 8; i++) {
            if (bk[i] >= 0) {
                int p = lex[bk[i]] + atomicAdd(&lh[bk[i]], 1);
                srec[p] = rec[i];
                sb[p] = (short)bk[i];
            }
        }
        __syncthreads();
        int total = scanbuf[NB - 1];
        for (int idx = t; idx < total; idx += 256) {
            int bb = sb[idx];
            ebuf[gbase[bb] + (idx - lex[bb])] = srec[idx];
        }
        return;
    }
    // ---------- weight prep / flags ----------
    int wb = b - SC_BLOCKS;
    if (wb == 136) {
        unsigned int* f4 = (unsigned int*)flags;
        for (int i = t; i < 25000; i += 256) f4[i] = 0u;
        __syncthreads();
        for (int i = t; i < N_PAIRS; i += 256) {
            flags[uidx[i]] = 1;
            flags[iidx[i]] = 1;
        }
        return;
    }
    if (wb < 96) {
        int idx = wb * 256 + t;
        if (idx >= 192 * IN_FEATS) return;
        int j = idx / IN_FEATS, k = idx % IN_FEATS;
        float v;
        if (j < 160) {
            int r = j >> 5, o = j & 31;
            v = comp1[r * 2 + 0] * V1[(size_t)(0 * IN_FEATS + k) * 32 + o]
              + comp1[r * 2 + 1] * V1[(size_t)(1 * IN_FEATS + k) * 32 + o];
        } else {
            v = loop1[k * 32 + (j - 160)];
        }
        Wbf1[idx] = bf16_1(v);
        return;
    }
    const float *V, *loopw;
    unsigned short* Wc;
    int idx;
    if (wb < 116) { V = V2; loopw = loop2; Wc = Wcat2; idx = (wb - 96) * 256 + t; }
    else          { V = V3; loopw = loop3; Wc = Wcat3; idx = (wb - 116) * 256 + t; }
    if (idx >= 32 * 160) return;
    int col = idx / 160, k = idx % 160;
    int seg = k >> 5, inner = k & 31;
    float v;
    if (seg < 2)      v = V[inner * 32 + col];           // basis 0 (hi, lo)
    else if (seg < 4) v = V[(32 + inner) * 32 + col];    // basis 1 (hi, lo)
    else              v = loopw[inner * 32 + col];       // self-loop
    Wc[idx] = bf16_1(v);
}

// ---------------- k2: bsort (blocks 0..391) || transform L1 (392..1016), 512 thr ----------

#define SMEM2_BYTES 19456    // 2 x (As 4352 + tb 5376) = 19456 >= bsort's 7176

__global__ __launch_bounds__(512) void k_bsort_tl1(
    const int* __restrict__ gcur, const int2* __restrict__ ebuf,
    int2* __restrict__ esort, int* __restrict__ offsets,
    const float* __restrict__ xin,
    const unsigned short* __restrict__ Wbf, const float* __restrict__ bias,
    unsigned short* __restrict__ xs16, float* __restrict__ aggout) {
    __shared__ __attribute__((aligned(16))) char smem2[SMEM2_BYTES];
    int b = blockIdx.x;
    int t = threadIdx.x;
    if (b < NBSORT) {
        // ---------- per-half-bucket counting sort -> CSR ----------
        int* hist = (int*)smem2;                 // 2048
        int* incl = (int*)(smem2 + 2048);        // 2048 -> 4096
        int* cur  = (int*)(smem2 + 4096);        // 2048 -> 6144
        int* bs   = (int*)(smem2 + 6144);        // 1024 -> 7168
        int* sBC  = (int*)(smem2 + 7168);        // [0]=sBase [1]=sCnt
        int bb = b >> 1, h = b & 1;
        if (t < 256) bs[t] = (t < NB) ? gcur[t] : 0;
        __syncthreads();
        for (int off = 1; off < 256; off <<= 1) {
            int v = 0;
            if (t < 256 && t >= off) v = bs[t - off];
            __syncthreads();
            if (t < 256) bs[t] += v;
            __syncthreads();
        }
        if (t == 0) { sBC[1] = gcur[bb]; sBC[0] = bs[bb] - gcur[bb]; }
        hist[t] = 0;
        __syncthreads();
        int cnt = sBC[1], gbase = sBC[0];
        const int2* slab = ebuf + (size_t)bb * BCAP;
        for (int e = t; e < cnt; e += 512) {
            int dl = ((unsigned)slab[e].x) >> 23;
            atomicAdd(&hist[dl], 1);
        }
        __syncthreads();
        incl[t] = hist[t];
        __syncthreads();
        for (int off = 1; off < 512; off <<= 1) {
            int v = 0;
            if (t >= off) v = incl[t - off];
            __syncthreads();
            incl[t] += v;
            __syncthreads();
        }
        int ex = incl[t] - hist[t];
        cur[t] = ex;
        if ((t >> 8) == h) {
            int n = (bb << 9) + t;
            if (n <= N_NODES) offsets[n] = gbase + ex;
        }
        if (bb == NB - 1 && h == 1 && t == 0) offsets[N_NODES] = N_EDGES;
        __syncthreads();
        for (int e = t; e < cnt; e += 512) {
            int2 pk = slab[e];
            int dl = ((unsigned)pk.x) >> 23;
            if ((dl >> 8) == h) {
                int pos = gbase + atomicAdd(&cur[dl], 1);
                int2 rec;
                rec.x = pk.x & 0x7fffff;
                rec.y = pk.y;
                esort[pos] = rec;
            }
        }
        return;
    }
    // ---------- transform L1: two independent 256-thread halves ----------
    int half = t >> 8;                 // 0 / 1
    int tl   = t & 255;
    char* basep = smem2 + half * 9728;
    unsigned short* As = (unsigned short*)basep;          // 16*136*2 = 4352 B
    unsigned short* tb = (unsigned short*)(basep + 4352); // 16*168*2 = 5376 B
    int bb = (b - NBSORT) * 2 + half;  // 0..1249
    int wv = tl >> 6, lane = tl & 63;
    int q = lane >> 4, n16 = lane & 15;
    short8 bfr[3][4];
#pragma unroll
    for (int i = 0; i < 3; i++) {
        int tt = wv * 3 + i;
#pragma unroll
        for (int ks = 0; ks < 4; ks++)
            bfr[i][ks] = *(const short8*)(Wbf + (tt * 16 + n16) * 128 + ks * 32 + q * 8);
    }
    float bv0 = bias[n16], bv1 = bias[16 + n16];
    int node_l = tl >> 4;
    int seg    = tl & 15;
    int g0 = bb * 5;
    float4 p0, p1;
    {
        const float* xr = xin + ((size_t)(g0 * 16 + node_l)) * 128 + seg * 8;
        p0 = *(const float4*)xr;
        p1 = *(const float4*)(xr + 4);
    }
    for (int gi = 0; gi < 5; gi++) {
        int g = g0 + gi;
        int n0 = g * 16;
        __syncthreads();   // As + tb free [both halves in lockstep]
        {
            uint4 v;
            v.x = pack_bf16(p0.x, p0.y);
            v.y = pack_bf16(p0.z, p0.w);
            v.z = pack_bf16(p1.x, p1.y);
            v.w = pack_bf16(p1.z, p1.w);
            *(uint4*)(As + node_l * 136 + seg * 8) = v;
        }
        __syncthreads();
        if (gi + 1 < 5) {
            const float* xr = xin + ((size_t)((g + 1) * 16 + node_l)) * 128 + seg * 8;
            p0 = *(const float4*)xr;
            p1 = *(const float4*)(xr + 4);
        }
        short8 afr[4];
#pragma unroll
        for (int ks = 0; ks < 4; ks++)
            afr[ks] = *(const short8*)(As + n16 * 136 + ks * 32 + q * 8);
        f32x4 d[3];
        f32x4 z = {0.f, 0.f, 0.f, 0.f};
#pragma unroll
        for (int i = 0; i < 3; i++) d[i] = z;
#pragma unroll
        for (int i = 0; i < 3; i++)
#pragma unroll
            for (int ks = 0; ks < 4; ks++)
                d[i] = __builtin_amdgcn_mfma_f32_16x16x32_bf16(afr[ks], bfr[i][ks], d[i], 0, 0, 0);
        // epilogue: tts 0..9 -> LDS transpose; tts 10,11 -> aggA direct (f32)
#pragma unroll
        for (int i = 0; i < 3; i++) {
            int tt = wv * 3 + i;
            if (tt < 10) {
#pragma unroll
                for (int r = 0; r < 4; r++)
                    tb[(q * 4 + r) * 168 + tt * 16 + n16] = bf16_1(d[i][r]);
            } else {
                float bv = (tt == 10) ? bv0 : bv1;
                int o = (tt - 10) * 16 + n16;
#pragma unroll
                for (int r = 0; r < 4; r++) {
                    int node = n0 + q * 4 + r;
                    aggout[(size_t)node * 32 + o] = d[i][r] + bv;
                }
            }
        }
        __syncthreads();
        // coalesced xs16 flush: 16 nodes x 160 shorts = 320 chunks of 8 shorts
        for (int c = tl; c < 320; c += 256) {
            int node_i = c / 20, part = c % 20;
            short8 vv = *(const short8*)(tb + node_i * 168 + part * 8);
            *(short8*)(xs16 + (size_t)(n0 + node_i) * 160 + part * 8) = vv;
        }
    }
}

// ---------------- layer-1 aggregation (gathers per-etype xs16) ----------------

__global__ __launch_bounds__(256) void k_agg1(
    const int* __restrict__ offsets, const int2* __restrict__ esort,
    const unsigned int* __restrict__ xrel16, const float* __restrict__ agg,
    float* __restrict__ concat, unsigned int* __restrict__ hrel_out,
    const unsigned char* __restrict__ flags) {
    int v = blockIdx.x * 32 + (threadIdx.x >> 3);
    int o = threadIdx.x & 7;
    int s0 = offsets[v], s1 = offsets[v + 1];
    float4 a0 = *(const float4*)(agg + (size_t)v * 32 + o * 4);
    float acc0 = a0.x, acc1 = a0.y, acc2 = a0.z, acc3 = a0.w;
    int last = s1 - 1;
    for (int e = s0; e < s1; e += 16) {
        int addr[16];
        float m[16];
#pragma unroll
        for (int i = 0; i < 16; i++) {
            int ei = e + i;
            int ec = (ei <= last) ? ei : last;
            int2 pk = esort[ec];
            int low = pk.x;
            addr[i] = (low >> 4) * 80 + (low & 15) * 16;
            m[i] = (ei <= last) ? __int_as_float(pk.y) : 0.f;
        }
        uint2 xw[16];
#pragma unroll
        for (int i = 0; i < 16; i++)
            xw[i] = *(const uint2*)(xrel16 + (unsigned)addr[i] + o * 2);
#pragma unroll
        for (int i = 0; i < 16; i++) {
            float f0 = __uint_as_float(xw[i].x << 16);
            float f1 = __uint_as_float(xw[i].x & 0xffff0000u);
            float f2 = __uint_as_float(xw[i].y << 16);
            float f3 = __uint_as_float(xw[i].y & 0xffff0000u);
            acc0 = fmaf(m[i], f0, acc0);
            acc1 = fmaf(m[i], f1, acc1);
            acc2 = fmaf(m[i], f2, acc2);
            acc3 = fmaf(m[i], f3, acc3);
        }
    }
    float4 r;
    r.x = tanhf(acc0); r.y = tanhf(acc1); r.z = tanhf(acc2); r.w = tanhf(acc3);
    if (flags[v])
        *(float4*)(concat + (size_t)v * 96 + o * 4) = r;
    hrel_out[v * 16 + o * 2]     = pack_bf16(r.x, r.y);
    hrel_out[v * 16 + o * 2 + 1] = pack_bf16(r.z, r.w);
}

// ---------------- layer 2: basis-space aggregation + split-bf16 MFMA epilogue ----------

__global__ __launch_bounds__(256) void k_agg23(
    const int* __restrict__ offsets, const int2* __restrict__ esort,
    const unsigned int* __restrict__ hrel_in, const float* __restrict__ comp,
    const unsigned short* __restrict__ Wcat, const float* __restrict__ bias,
    float* __restrict__ concat, int hoff, unsigned int* __restrict__ hrel_out,
    const unsigned char* __restrict__ flags) {
    __shared__ unsigned int hbf[32][84];
    __shared__ float2 cLds[5];
    int t = threadIdx.x;
    if (t < 5) cLds[t] = ((const float2*)comp)[t];
    int nl = t >> 3;
    int v = blockIdx.x * 32 + nl;
    int o = t & 7;
    int s0 = offsets[v], s1 = offsets[v + 1];
    __syncthreads();
    float y00 = 0.f, y01 = 0.f, y02 = 0.f, y03 = 0.f;
    float y10 = 0.f, y11 = 0.f, y12 = 0.f, y13 = 0.f;
    int last = s1 - 1;
    for (int e = s0; e < s1; e += 16) {
        int addr[16];
        float c0[16], c1[16];
#pragma unroll
        for (int i = 0; i < 16; i++) {
            int ei = e + i;
            int ec = (ei <= last) ? ei : last;
            int2 pk = esort[ec];
            int low = pk.x;
            addr[i] = low & 0x7ffff0;            // src*16 (uint units)
            float2 cc = cLds[low & 15];
            float m = (ei <= last) ? __int_as_float(pk.y) : 0.f;
            c0[i] = m * cc.x;
            c1[i] = m * cc.y;
        }
        uint2 xw[16];
#pragma unroll
        for (int i = 0; i < 16; i++)
            xw[i] = *(const uint2*)(hrel_in + (unsigned)addr[i] + o * 2);
#pragma unroll
        for (int i = 0; i < 16; i++) {
            float f0 = __uint_as_float(xw[i].x << 16);
            float f1 = __uint_as_float(xw[i].x & 0xffff0000u);
            float f2 = __uint_as_float(xw[i].y << 16);
            float f3 = __uint_as_float(xw[i].y & 0xffff0000u);
            y00 = fmaf(c0[i], f0, y00); y10 = fmaf(c1[i], f0, y10);
            y01 = fmaf(c0[i], f1, y01); y11 = fmaf(c1[i], f1, y11);
            y02 = fmaf(c0[i], f2, y02); y12 = fmaf(c1[i], f2, y12);
            y03 = fmaf(c0[i], f3, y03); y13 = fmaf(c1[i], f3, y13);
        }
    }
    unsigned int hi, lo;
    split_bf16_2(y00, y01, hi, lo);
    hbf[nl][o * 2]          = hi;  hbf[nl][16 + o * 2]     = lo;
    split_bf16_2(y02, y03, hi, lo);
    hbf[nl][o * 2 + 1]      = hi;  hbf[nl][16 + o * 2 + 1] = lo;
    split_bf16_2(y10, y11, hi, lo);
    hbf[nl][32 + o * 2]     = hi;  hbf[nl][48 + o * 2]     = lo;
    split_bf16_2(y12, y13, hi, lo);
    hbf[nl][32 + o * 2 + 1] = hi;  hbf[nl][48 + o * 2 + 1] = lo;
    *(uint2*)&hbf[nl][64 + o * 2] = *(const uint2*)(hrel_in + v * 16 + o * 2);
    __syncthreads();
    int wv = t >> 6, lane = t & 63;
    int q = lane >> 4, n16 = lane & 15;
    int gg = wv & 1;
    int tt = wv >> 1;
    f32x4 d = {0.f, 0.f, 0.f, 0.f};
#pragma unroll
    for (int ks = 0; ks < 5; ks++) {
        short8 afr = *(const short8*)&hbf[gg * 16 + n16][ks * 16 + q * 4];
        short8 bfr = *(const short8*)(Wcat + (tt * 16 + n16) * 160 + ks * 32 + q * 8);
        d = __builtin_amdgcn_mfma_f32_16x16x32_bf16(afr, bfr, d, 0, 0, 0);
    }
    float bv = bias[tt * 16 + n16];
    int n0 = blockIdx.x * 32 + gg * 16;
#pragma unroll
    for (int r = 0; r < 4; r++) {
        int node = n0 + q * 4 + r;
        float h = tanhf(d[r] + bv);
        if (flags[node])
            concat[(size_t)node * 96 + hoff + tt * 16 + n16] = h;
        if (hrel_out)
            ((unsigned short*)hrel_out)[node * 32 + tt * 16 + n16] = bf16_1(h);
    }
}

// ---------------- layer 3 RESTRICTED: only the 8192 MLP-referenced nodes ----------

__global__ __launch_bounds__(256) void k_agg3s(
    const int* __restrict__ offsets, const int2* __restrict__ esort,
    const unsigned int* __restrict__ hrel_in, const float* __restrict__ comp,
    const unsigned short* __restrict__ Wcat, const float* __restrict__ bias,
    const int* __restrict__ uidx, const int* __restrict__ iidx,
    float* __restrict__ concat) {
    __shared__ unsigned int hbf[32][84];
    __shared__ float2 cLds[5];
    __shared__ int nlist[32];
    int t = threadIdx.x;
    if (t < 5) cLds[t] = ((const float2*)comp)[t];
    if (t < 32) {
        int slot = blockIdx.x * 32 + t;   // 256 blocks x 32 = 8192 slots exact
        nlist[t] = (slot < N_PAIRS) ? uidx[slot] : iidx[slot - N_PAIRS];
    }
    __syncthreads();
    int nl = t >> 3;
    int v = nlist[nl];
    int o = t & 7;
    int s0 = offsets[v], s1 = offsets[v + 1];
    float y00 = 0.f, y01 = 0.f, y02 = 0.f, y03 = 0.f;
    float y10 = 0.f, y11 = 0.f, y12 = 0.f, y13 = 0.f;
    int last = s1 - 1;
    for (int e = s0; e < s1; e += 16) {
        int addr[16];
        float c0[16], c1[16];
#pragma unroll
        for (int i = 0; i < 16; i++) {
            int ei = e + i;
            int ec = (ei <= last) ? ei : last;
            int2 pk = esort[ec];
            int low = pk.x;
            addr[i] = low & 0x7ffff0;
            float2 cc = cLds[low & 15];
            float m = (ei <= last) ? __int_as_float(pk.y) : 0.f;
            c0[i] = m * cc.x;
            c1[i] = m * cc.y;
        }
        uint2 xw[16];
#pragma unroll
        for (int i = 0; i < 16; i++)
            xw[i] = *(const uint2*)(hrel_in + (unsigned)addr[i] + o * 2);
#pragma unroll
        for (int i = 0; i < 16; i++) {
            float f0 = __uint_as_float(xw[i].x << 16);
            float f1 = __uint_as_float(xw[i].x & 0xffff0000u);
            float f2 = __uint_as_float(xw[i].y << 16);
            float f3 = __uint_as_float(xw[i].y & 0xffff0000u);
            y00 = fmaf(c0[i], f0, y00); y10 = fmaf(c1[i], f0, y10);
            y01 = fmaf(c0[i], f1, y01); y11 = fmaf(c1[i], f1, y11);
            y02 = fmaf(c0[i], f2, y02); y12 = fmaf(c1[i], f2, y12);
            y03 = fmaf(c0[i], f3, y03); y13 = fmaf(c1[i], f3, y13);
        }
    }
    unsigned int hi, lo;
    split_bf16_2(y00, y01, hi, lo);
    hbf[nl][o * 2]          = hi;  hbf[nl][16 + o * 2]     = lo;
    split_bf16_2(y02, y03, hi, lo);
    hbf[nl][o * 2 + 1]      = hi;  hbf[nl][16 + o * 2 + 1] = lo;
    split_bf16_2(y10, y11, hi, lo);
    hbf[nl][32 + o * 2]     = hi;  hbf[nl][48 + o * 2]     = lo;
    split_bf16_2(y12, y13, hi, lo);
    hbf[nl][32 + o * 2 + 1] = hi;  hbf[nl][48 + o * 2 + 1] = lo;
    *(uint2*)&hbf[nl][64 + o * 2] = *(const uint2*)(hrel_in + v * 16 + o * 2);
    __syncthreads();
    int wv = t >> 6, lane = t & 63;
    int q = lane >> 4, n16 = lane & 15;
    int gg = wv & 1;
    int tt = wv >> 1;
    f32x4 d = {0.f, 0.f, 0.f, 0.f};
#pragma unroll
    for (int ks = 0; ks < 5; ks++) {
        short8 afr = *(const short8*)&hbf[gg * 16 + n16][ks * 16 + q * 4];
        short8 bfr = *(const short8*)(Wcat + (tt * 16 + n16) * 160 + ks * 32 + q * 8);
        d = __builtin_amdgcn_mfma_f32_16x16x32_bf16(afr, bfr, d, 0, 0, 0);
    }
    float bv = bias[tt * 16 + n16];
    int base = gg * 16 + q * 4;
#pragma unroll
    for (int r = 0; r < 4; r++) {
        int node = nlist[base + r];
        float h = tanhf(d[r] + bv);
        concat[(size_t)node * 96 + 64 + tt * 16 + n16] = h;
    }
}

// ---------------- MLP head ----------------

__global__ void k_mlp(const float* __restrict__ concat, const int* __restrict__ uidx,
                      const int* __restrict__ iidx,
                      const float* __restrict__ w1, const float* __restrict__ bw1,
                      const float* __restrict__ w2, const float* __restrict__ bw2,
                      float* __restrict__ out) {
    __shared__ float feats[192];
    __shared__ float red[2];
    int p = blockIdx.x;
    int t = threadIdx.x;   // 128 threads
    int u = uidx[p], it = iidx[p];
    for (int k = t; k < 192; k += 128)
        feats[k] = (k < 96) ? concat[(size_t)u * 96 + k] : concat[(size_t)it * 96 + (k - 96)];
    __syncthreads();
    float acc = bw1[t];
    for (int k = 0; k < 192; k++) acc += feats[k] * w1[k * 128 + t];
    float h = fmaxf(acc, 0.f);
    float part = h * w2[t];
    for (int off = 32; off > 0; off >>= 1) part += __shfl_down(part, off, 64);
    if ((t & 63) == 0) red[t >> 6] = part;
    __syncthreads();
    if (t == 0) out[p] = red[0] + red[1] + bw2[0];
}

// ---------------- launch ----------------

extern "C" void kernel_launch(void* const* d_in, const int* in_sizes, int n_in,
                              void* d_out, int out_size, void* d_ws, size_t ws_size,
                              hipStream_t stream) {
    const float* x         = (const float*)d_in[0];
    const float* edge_mask = (const float*)d_in[1];
    const int*   etype     = (const int*)d_in[2];
    const int*   src       = (const int*)d_in[3];
    const int*   dst       = (const int*)d_in[4];
    const int*   users_idx = (const int*)d_in[5];
    const int*   items_idx = (const int*)d_in[6];
    const float* V1        = (const float*)d_in[7];
    const float* comp1     = (const float*)d_in[8];
    const float* loop1     = (const float*)d_in[9];
    const float* b1        = (const float*)d_in[10];
    const float* V2        = (const float*)d_in[11];
    const float* comp2     = (const float*)d_in[12];
    const float* loop2     = (const float*)d_in[13];
    const float* b2        = (const float*)d_in[14];
    const float* V3        = (const float*)d_in[15];
    const float* comp3     = (const float*)d_in[16];
    const float* loop3     = (const float*)d_in[17];
    const float* b3        = (const float*)d_in[18];
    const float* w1        = (const float*)d_in[19];
    const float* bw1       = (const float*)d_in[20];
    const float* w2        = (const float*)d_in[21];
    const float* bw2       = (const float*)d_in[22];
    float* out = (float*)d_out;

    uintptr_t w = (uintptr_t)d_ws;
    auto al = [&](size_t bytes) { uintptr_t p = (w + 255) & ~(uintptr_t)255; w = p + bytes; return p; };
    int*   gcur    = (int*)al(sizeof(int) * NB);
    unsigned char* flags = (unsigned char*)al(100000);
    int*   offsets = (int*)al(sizeof(int) * (N_NODES + 1));
    int2*  ebuf    = (int2*)al(sizeof(int2) * (size_t)NB * BCAP);
    unsigned int* xs16  = (unsigned int*)al(sizeof(unsigned int) * (size_t)N_NODES * 80);
    unsigned int* hrel1 = (unsigned int*)al(sizeof(unsigned int) * (size_t)N_NODES * 16);
    unsigned int* hrel2 = (unsigned int*)al(sizeof(unsigned int) * (size_t)N_NODES * 16);
    int2*  esort   = (int2*)al(sizeof(int2) * N_EDGES);
    unsigned short* Wbf1  = (unsigned short*)al(sizeof(unsigned short) * 192 * IN_FEATS);
    unsigned short* Wcat2 = (unsigned short*)al(sizeof(unsigned short) * 32 * 160);
    unsigned short* Wcat3 = (unsigned short*)al(sizeof(unsigned short) * 32 * 160);
    float* aggA    = (float*)al(sizeof(float) * (size_t)N_NODES * 32);
    float* concat  = (float*)al(sizeof(float) * (size_t)N_NODES * 96);

    hipMemsetAsync(gcur, 0, sizeof(int) * NB, stream);

    // k1: scatter + weight prep + flags
    k_scatter_wprep<<<SC_BLOCKS + WP_BLOCKS, 256, 0, stream>>>(
        src, dst, etype, edge_mask, gcur, ebuf,
        V1, comp1, loop1, V2, loop2, V3, loop3, Wbf1, Wcat2, Wcat3,
        users_idx, items_idx, flags);
    // k2: CSR bucket-sort || transform L1
    k_bsort_tl1<<<NBSORT + TD_BLOCKS, 512, 0, stream>>>(
        gcur, ebuf, esort, offsets,
        x, Wbf1, b1, (unsigned short*)xs16, aggA);

    const int agrid = N_NODES / 32;   // 3125, exact

    // layer 1 aggregation -> h1 (hrel1 bf16; concat only where flagged)
    k_agg1<<<agrid, 256, 0, stream>>>(offsets, esort, xs16, aggA, concat, hrel1, flags);
    // layer 2 (full: h2 is the gather source for layer 3)
    k_agg23<<<agrid, 256, 0, stream>>>(offsets, esort, hrel1, comp2, Wcat2, b2,
                                       concat, 32, hrel2, flags);
    // layer 3: only the 8192 MLP-referenced nodes
    k_agg3s<<<256, 256, 0, stream>>>(offsets, esort, hrel2, comp3, Wcat3, b3,
                                     users_idx, items_idx, concat);

    k_mlp<<<N_PAIRS, 128, 0, stream>>>(concat, users_idx, items_idx, w1, bw1, w2, bw2, out);
}